// Round 1
// baseline (493.486 us; speedup 1.0000x reference)
//
#include <hip/hip_runtime.h>
#include <hip/hip_bf16.h>
#include <math.h>

#define EMBED 768
#define HEADS 12
#define HEAD_DIM 64
#define HIDDEN 3072
#define SEQ 1024
#define BATCH 8
#define TOKENS (SEQ*BATCH)

typedef unsigned short u16;
typedef __attribute__((ext_vector_type(8))) short bf16x8;
typedef __attribute__((ext_vector_type(4))) float floatx4;

__device__ __forceinline__ u16 f2bf(float f){
    union { float f; unsigned u; } v; v.f = f;
    unsigned r = v.u + 0x7fffu + ((v.u >> 16) & 1u);
    return (u16)(r >> 16);
}

__device__ __forceinline__ void gload16(const void* g, void* l){
    __builtin_amdgcn_global_load_lds((const __attribute__((address_space(1))) void*)g,
                                     (__attribute__((address_space(3))) void*)l, 16, 0, 0);
}

// ---------------- weight cast+transpose: W (K x N) fp32 -> Wt (N x K) bf16 ----------------
__global__ void transpose_cast(const float* __restrict__ W, u16* __restrict__ Wt, int K, int N){
    __shared__ float tile[32][33];
    int n0 = blockIdx.x * 32, k0 = blockIdx.y * 32;
    int tx = threadIdx.x, ty = threadIdx.y;  // 32 x 8
    #pragma unroll
    for(int i=0;i<32;i+=8) tile[ty+i][tx] = W[(size_t)(k0+ty+i)*N + n0+tx];
    __syncthreads();
    #pragma unroll
    for(int i=0;i<32;i+=8) Wt[(size_t)(n0+ty+i)*K + k0+tx] = f2bf(tile[tx][ty+i]);
}

// ---------------- layernorm: fp32 in -> bf16 out. one wave per row of 768 ----------------
__global__ __launch_bounds__(256) void ln_kernel(const float* __restrict__ x, const float* __restrict__ g,
                                                 const float* __restrict__ b, u16* __restrict__ out){
    int row  = blockIdx.x * 4 + (threadIdx.x >> 6);
    int lane = threadIdx.x & 63;
    const float* xr = x + (size_t)row * EMBED;
    float v[12];
    float s = 0.f;
    #pragma unroll
    for(int i=0;i<12;i++){ v[i] = xr[lane + i*64]; s += v[i]; }
    #pragma unroll
    for(int o=32;o>0;o>>=1) s += __shfl_xor(s, o);
    float mu = s * (1.0f/EMBED);
    float s2 = 0.f;
    #pragma unroll
    for(int i=0;i<12;i++){ float d = v[i]-mu; s2 += d*d; }
    #pragma unroll
    for(int o=32;o>0;o>>=1) s2 += __shfl_xor(s2, o);
    float rstd = rsqrtf(s2*(1.0f/EMBED) + 1e-5f);
    u16* orow = out + (size_t)row * EMBED;
    #pragma unroll
    for(int i=0;i<12;i++){
        int c = lane + i*64;
        orow[c] = f2bf((v[i]-mu)*rstd*g[c] + b[c]);
    }
}

// ---------------- GEMM: C(MxN) = A(MxK,bf16) @ Bt(NxK,bf16)^T  [+bias][epilogue] ----------------
// EPI 0: bf16 out (optional bias). EPI 1: bias + exact GELU -> bf16. EPI 2: bias + fp32 residual -> fp32.
template<int EPI>
__global__ __launch_bounds__(256) void gemm_bt(const u16* __restrict__ A, const u16* __restrict__ Bt,
        void* __restrict__ Cout, const float* __restrict__ bias, const float* __restrict__ res,
        int M, int N, int K){
    __shared__ __align__(16) u16 As[128*32];
    __shared__ __align__(16) u16 Bs[128*32];
    int tid  = threadIdx.x;
    int wave = tid >> 6, lane = tid & 63;
    int quad = lane >> 4, lm = lane & 15;
    int m0 = blockIdx.y * 128, n0 = blockIdx.x * 128;
    int wm = (wave & 1) * 64, wn = (wave >> 1) * 64;

    floatx4 acc[4][4];
    #pragma unroll
    for(int i=0;i<4;i++)
        #pragma unroll
        for(int j=0;j<4;j++) acc[i][j] = (floatx4){0.f,0.f,0.f,0.f};

    int sr = tid >> 2;          // 0..63
    int sc = (tid & 3) * 8;     // 0,8,16,24
    const u16* ga0 = A  + (size_t)(m0 + sr)      * K + sc;
    const u16* ga1 = A  + (size_t)(m0 + sr + 64) * K + sc;
    const u16* gb0 = Bt + (size_t)(n0 + sr)      * K + sc;
    const u16* gb1 = Bt + (size_t)(n0 + sr + 64) * K + sc;
    u16* lA0 = As + tid*8;
    u16* lA1 = As + 2048 + tid*8;
    u16* lB0 = Bs + tid*8;
    u16* lB1 = Bs + 2048 + tid*8;

    for(int k0=0; k0<K; k0+=32){
        __syncthreads();
        gload16(ga0 + k0, lA0);
        gload16(ga1 + k0, lA1);
        gload16(gb0 + k0, lB0);
        gload16(gb1 + k0, lB1);
        __syncthreads();
        bf16x8 af[4], bfr[4];
        #pragma unroll
        for(int i=0;i<4;i++){
            af[i]  = *(const bf16x8*)(As + (wm + i*16 + lm)*32 + quad*8);
            bfr[i] = *(const bf16x8*)(Bs + (wn + i*16 + lm)*32 + quad*8);
        }
        #pragma unroll
        for(int mf=0;mf<4;mf++)
            #pragma unroll
            for(int nf=0;nf<4;nf++)
                acc[mf][nf] = __builtin_amdgcn_mfma_f32_16x16x32_bf16(af[mf], bfr[nf], acc[mf][nf], 0, 0, 0);
    }

    #pragma unroll
    for(int nf=0;nf<4;nf++){
        int col = n0 + wn + nf*16 + lm;
        float bv = bias ? bias[col] : 0.f;
        #pragma unroll
        for(int mf=0;mf<4;mf++){
            int row0 = m0 + wm + mf*16 + quad*4;
            #pragma unroll
            for(int r=0;r<4;r++){
                float v = acc[mf][nf][r] + bv;
                size_t idx = (size_t)(row0 + r) * N + col;
                if(EPI == 1){
                    v = 0.5f * v * (1.0f + erff(v * 0.70710678118f));
                    ((u16*)Cout)[idx] = f2bf(v);
                } else if(EPI == 2){
                    ((float*)Cout)[idx] = v + res[idx];
                } else {
                    ((u16*)Cout)[idx] = f2bf(v);
                }
            }
        }
    }
}

// ---------------- flash attention: qkv bf16 (TOKENS x 2304), out bf16 (TOKENS x 768) ----------------
// grid: (qtile=16, head=12, batch=8), block 256 = 4 waves, each wave owns 16 q-rows.
__global__ __launch_bounds__(256) void attn_kernel(const u16* __restrict__ qkv, u16* __restrict__ out){
    int qt = blockIdx.x, h = blockIdx.y, b = blockIdx.z;
    int tid = threadIdx.x;
    int wave = tid >> 6, lane = tid & 63;
    int quad = lane >> 4, lm = lane & 15;

    __shared__ __align__(16) u16 Vt[64*80];        // [d][key], padded stride 80
    __shared__ __align__(16) u16 P[4][16*80];      // per-wave P tile [qrow][key]

    const size_t rs = 3*EMBED;
    const u16* base = qkv + (size_t)b * SEQ * rs;

    int qrow = qt*64 + wave*16 + lm;
    bf16x8 qf[2];
    #pragma unroll
    for(int ks=0; ks<2; ks++)
        qf[ks] = *(const bf16x8*)(base + (size_t)qrow*rs + h*64 + ks*32 + quad*8);

    float m_i[4], l_i[4];
    floatx4 o_acc[4];
    #pragma unroll
    for(int r=0;r<4;r++){ m_i[r] = -1e30f; l_i[r] = 0.f; }
    #pragma unroll
    for(int nf=0;nf<4;nf++) o_acc[nf] = (floatx4){0.f,0.f,0.f,0.f};

    u16* Pw = &P[wave][0];
    int vkey = tid & 63;
    int vd0  = (tid >> 6) * 16;
    const float scale = 0.125f;  // 1/sqrt(64)

    for(int kt=0; kt<16; kt++){
        __syncthreads();
        {   // stage V tile transposed: Vt[d][key]
            const u16* vp = base + (size_t)(kt*64 + vkey)*rs + 2*EMBED + h*64 + vd0;
            bf16x8 v0 = *(const bf16x8*)(vp);
            bf16x8 v1 = *(const bf16x8*)(vp + 8);
            #pragma unroll
            for(int j=0;j<8;j++){
                Vt[(vd0+j)*80   + vkey] = (u16)v0[j];
                Vt[(vd0+8+j)*80 + vkey] = (u16)v1[j];
            }
        }
        __syncthreads();

        // S = Q K^T for this wave's 16 rows x 64 keys
        floatx4 s[4];
        #pragma unroll
        for(int nf=0;nf<4;nf++){
            s[nf] = (floatx4){0.f,0.f,0.f,0.f};
            #pragma unroll
            for(int ks=0;ks<2;ks++){
                int krow = kt*64 + nf*16 + lm;
                bf16x8 kf = *(const bf16x8*)(base + (size_t)krow*rs + EMBED + h*64 + ks*32 + quad*8);
                s[nf] = __builtin_amdgcn_mfma_f32_16x16x32_bf16(qf[ks], kf, s[nf], 0, 0, 0);
            }
        }

        // online softmax (rows = quad*4 + r, cols spread over 16 lanes of quad)
        float p[4][4];
        float alpha[4];
        #pragma unroll
        for(int r=0;r<4;r++){
            float m = -1e30f;
            #pragma unroll
            for(int nf=0;nf<4;nf++){ p[nf][r] = s[nf][r]*scale; m = fmaxf(m, p[nf][r]); }
            m = fmaxf(m, __shfl_xor(m, 1));
            m = fmaxf(m, __shfl_xor(m, 2));
            m = fmaxf(m, __shfl_xor(m, 4));
            m = fmaxf(m, __shfl_xor(m, 8));
            float mn = fmaxf(m_i[r], m);
            alpha[r] = __expf(m_i[r] - mn);
            m_i[r] = mn;
            float sum = 0.f;
            #pragma unroll
            for(int nf=0;nf<4;nf++){ float e = __expf(p[nf][r]-mn); p[nf][r]=e; sum += e; }
            sum += __shfl_xor(sum, 1);
            sum += __shfl_xor(sum, 2);
            sum += __shfl_xor(sum, 4);
            sum += __shfl_xor(sum, 8);
            l_i[r] = l_i[r]*alpha[r] + sum;
        }
        #pragma unroll
        for(int nf=0;nf<4;nf++)
            #pragma unroll
            for(int r=0;r<4;r++) o_acc[nf][r] *= alpha[r];

        // P (C-layout) -> LDS, re-read in A-layout
        #pragma unroll
        for(int nf=0;nf<4;nf++)
            #pragma unroll
            for(int r=0;r<4;r++)
                Pw[(quad*4+r)*80 + nf*16 + lm] = f2bf(p[nf][r]);
        __syncthreads();

        // O += P @ V
        #pragma unroll
        for(int nf=0;nf<4;nf++){
            #pragma unroll
            for(int ks=0;ks<2;ks++){
                bf16x8 pa = *(const bf16x8*)(Pw + lm*80 + ks*32 + quad*8);
                bf16x8 vb = *(const bf16x8*)(Vt + (nf*16+lm)*80 + ks*32 + quad*8);
                o_acc[nf] = __builtin_amdgcn_mfma_f32_16x16x32_bf16(pa, vb, o_acc[nf], 0, 0, 0);
            }
        }
    }

    int token = b*SEQ + qt*64 + wave*16 + quad*4;
    #pragma unroll
    for(int nf=0;nf<4;nf++){
        #pragma unroll
        for(int r=0;r<4;r++){
            float v = o_acc[nf][r] / l_i[r];
            out[(size_t)(token + r)*EMBED + h*64 + nf*16 + lm] = f2bf(v);
        }
    }
}

extern "C" void kernel_launch(void* const* d_in, const int* in_sizes, int n_in,
                              void* d_out, int out_size, void* d_ws, size_t ws_size,
                              hipStream_t stream) {
    const float* x      = (const float*)d_in[0];
    const float* g1     = (const float*)d_in[1];
    const float* b1     = (const float*)d_in[2];
    const float* g2     = (const float*)d_in[3];
    const float* b2     = (const float*)d_in[4];
    const float* w_qkv  = (const float*)d_in[5];
    const float* w_proj = (const float*)d_in[6];
    const float* b_proj = (const float*)d_in[7];
    const float* w_fc1  = (const float*)d_in[8];
    const float* b_fc1  = (const float*)d_in[9];
    const float* w_fc2  = (const float*)d_in[10];
    const float* b_fc2  = (const float*)d_in[11];
    float* out = (float*)d_out;

    char* ws = (char*)d_ws;
    // layout (bytes):
    u16*   wqkv_t  = (u16*)  (ws + 0);          //  2304x768 bf16 -> 3,538,944
    u16*   wproj_t = (u16*)  (ws + 3538944);    //   768x768 bf16 -> 1,179,648
    u16*   wfc1_t  = (u16*)  (ws + 4718592);    //  3072x768 bf16 -> 4,718,592
    u16*   wfc2_t  = (u16*)  (ws + 9437184);    //  768x3072 bf16 -> 4,718,592
    float* x1      = (float*)(ws + 14155776);   //  8192x768 fp32 -> 25,165,824
    u16*   hbuf    = (u16*)  (ws + 39321600);   //  8192x768 bf16 -> 12,582,912
    u16*   qkv     = (u16*)  (ws + 51904512);   // 8192x2304 bf16 -> 37,748,736
    u16*   attn_o  = (u16*)  (ws + 89653248);   //  8192x768 bf16 -> 12,582,912 (end 102,236,160)
    u16*   fc1_o   = qkv;    // alias: qkv+attn_o region (50,331,648 B), lifetimes disjoint
    u16*   h2      = hbuf;   // alias: h dead after qkv GEMM

    dim3 tb(32, 8);
    transpose_cast<<<dim3(2304/32,  768/32), tb, 0, stream>>>(w_qkv,  wqkv_t,  768, 2304);
    transpose_cast<<<dim3( 768/32,  768/32), tb, 0, stream>>>(w_proj, wproj_t, 768,  768);
    transpose_cast<<<dim3(3072/32,  768/32), tb, 0, stream>>>(w_fc1,  wfc1_t,  768, 3072);
    transpose_cast<<<dim3( 768/32, 3072/32), tb, 0, stream>>>(w_fc2,  wfc2_t, 3072,  768);

    ln_kernel<<<TOKENS/4, 256, 0, stream>>>(x, g1, b1, hbuf);

    gemm_bt<0><<<dim3(2304/128, TOKENS/128), 256, 0, stream>>>(hbuf, wqkv_t, qkv, nullptr, nullptr, TOKENS, 2304, 768);

    attn_kernel<<<dim3(16, HEADS, BATCH), 256, 0, stream>>>(qkv, attn_o);

    gemm_bt<2><<<dim3( 768/128, TOKENS/128), 256, 0, stream>>>(attn_o, wproj_t, x1, b_proj, x, TOKENS, 768, 768);

    ln_kernel<<<TOKENS/4, 256, 0, stream>>>(x1, g2, b2, h2);

    gemm_bt<1><<<dim3(3072/128, TOKENS/128), 256, 0, stream>>>(h2, wfc1_t, fc1_o, b_fc1, nullptr, TOKENS, 3072, 768);

    gemm_bt<2><<<dim3( 768/128, TOKENS/128), 256, 0, stream>>>(fc1_o, wfc2_t, out, b_fc2, x1, TOKENS, 768, 3072);
}